// Round 14
// baseline (603.681 us; speedup 1.0000x reference)
//
#include <hip/hip_runtime.h>

#define N_NODES 20000
#define E_EDGES 160000
#define ET (E_EDGES + N_NODES)   // 180000 with self-loops
#define IN_CH 128
#define HID 1296
#define HEADS 36
#define CPH 36
#define OUT_CH 128
#define KP2 1408                 // HID padded to 2*704 (704=11*64) for gemm2 BK=64 split-K
#define NEG_SLOPE 0.2f

typedef __attribute__((ext_vector_type(8))) short bf16x8;
typedef __attribute__((ext_vector_type(8))) unsigned short ushort8;
typedef __attribute__((ext_vector_type(4))) float floatx4;

__device__ __forceinline__ float bf2f(unsigned short u) {
    union { unsigned int i; float f; } c; c.i = ((unsigned int)u) << 16; return c.f;
}
__device__ __forceinline__ unsigned short f2bf(float f) {
    union { float f; unsigned int i; } c; c.f = f;
    unsigned int r = c.i + 0x7FFF + ((c.i >> 16) & 1);   // round-to-nearest-even
    return (unsigned short)(r >> 16);
}
__device__ __forceinline__ float lrelu(float v) {
    return (v > 0.f) ? v : NEG_SLOPE * v;
}

// ------- prep+count (fused, range-partitioned): casts + degree count -------
#define NX (N_NODES * IN_CH / 4)      // 640000 float4 units
#define NW1 (HID * IN_CH)             // 165888
#define NW2 (OUT_CH * KP2)            // 180224
#define NPREP (NX + NW1 + NW2)
__global__ __launch_bounds__(256) void k_prepcnt(const float* __restrict__ x,
                                                 unsigned short* __restrict__ xb,
                                                 const float* __restrict__ W1,
                                                 unsigned short* __restrict__ W1T,
                                                 const float* __restrict__ W2,
                                                 unsigned short* __restrict__ W2T,
                                                 const int* __restrict__ ei,
                                                 int* __restrict__ cnt) {
    int gid = blockIdx.x * 256 + threadIdx.x;
    if (gid < NX) {
        float4 v = ((const float4*)x)[gid];
        ushort4 o; o.x = f2bf(v.x); o.y = f2bf(v.y); o.z = f2bf(v.z); o.w = f2bf(v.w);
        ((ushort4*)xb)[gid] = o;
    } else if (gid < NX + NW1) {
        int g = gid - NX;
        int n = g >> 7, k = g & 127;
        W1T[g] = f2bf(W1[(size_t)k * HID + n]);
    } else if (gid < NPREP) {
        int g = gid - NX - NW1;
        int n = g / KP2, k = g - n * KP2;
        W2T[g] = (k < HID) ? f2bf(W2[(size_t)k * OUT_CH + n]) : 0;
    } else if (gid < NPREP + ET) {
        int e = gid - NPREP;
        int d = (e < E_EDGES) ? ei[E_EDGES + e] : (e - E_EDGES);
        atomicAdd(&cnt[d], 1);
    }
}

// ------- GEMM1 (MFMA) + fused alpha1: h1b = xb@W1T^T; as1/ad1 per (node,head) dots -------
// col-block = 144 = exactly 4 heads -> each (n,h) is produced by exactly one block
// (plain stores, no global atomics). 128x144 tile, 4 waves, wave tile 32x144.
__global__ __launch_bounds__(256) void k_gemm1(const unsigned short* __restrict__ xb,
                                               const unsigned short* __restrict__ W1T,
                                               const float* __restrict__ a_src1,
                                               const float* __restrict__ a_dst1,
                                               unsigned short* __restrict__ h1b,
                                               float* __restrict__ as1,
                                               float* __restrict__ ad1) {
    __shared__ unsigned short As[128][136];
    __shared__ unsigned short Bs[144][136];
    __shared__ float part[128][4][2];
    int tid = threadIdx.x;
    int r0 = blockIdx.x * 128;
    int n0 = blockIdx.y * 144;          // 9 col-blocks: 9*144 = 1296 exact
    for (int i = tid; i < 128 * 4 * 2; i += 256) ((float*)part)[i] = 0.f;
#pragma unroll
    for (int i = 0; i < 8; i++) {
        int c = tid + i * 256;
        int row = c >> 4, kc = (c & 15) * 8;
        int gr = min(r0 + row, N_NODES - 1);
        *(bf16x8*)&As[row][kc] = *(const bf16x8*)(xb + (size_t)gr * IN_CH + kc);
    }
#pragma unroll
    for (int i = 0; i < 9; i++) {
        int c = tid + i * 256;          // < 2304 = 144*16
        int row = c >> 4, kc = (c & 15) * 8;
        *(bf16x8*)&Bs[row][kc] = *(const bf16x8*)(W1T + (size_t)(n0 + row) * IN_CH + kc);
    }
    __syncthreads();
    int lane = tid & 63, w = tid >> 6;
    int quad = lane >> 4, l15 = lane & 15;
    int mbase = w * 32;
    floatx4 acc[2][9];
#pragma unroll
    for (int i = 0; i < 2; i++)
#pragma unroll
        for (int j = 0; j < 9; j++) acc[i][j] = (floatx4){0.f, 0.f, 0.f, 0.f};
#pragma unroll
    for (int kc = 0; kc < 128; kc += 32) {
        bf16x8 a0 = *(const bf16x8*)&As[mbase + l15][kc + quad * 8];
        bf16x8 a1 = *(const bf16x8*)&As[mbase + 16 + l15][kc + quad * 8];
#pragma unroll
        for (int j = 0; j < 9; j++) {
            bf16x8 b = *(const bf16x8*)&Bs[j * 16 + l15][kc + quad * 8];
            acc[0][j] = __builtin_amdgcn_mfma_f32_16x16x32_bf16(a0, b, acc[0][j], 0, 0, 0);
            acc[1][j] = __builtin_amdgcn_mfma_f32_16x16x32_bf16(a1, b, acc[1][j], 0, 0, 0);
        }
    }
    int hb4 = blockIdx.y * 4;
#pragma unroll
    for (int i = 0; i < 2; i++)
#pragma unroll
        for (int j = 0; j < 9; j++) {
            int colc = n0 + j * 16 + l15;       // < 1296 always
            int hl = colc / 36 - hb4;           // 0..3
            float av = a_src1[colc];
            float dv = a_dst1[colc];
#pragma unroll
            for (int r = 0; r < 4; r++) {
                int rowl = mbase + i * 16 + quad * 4 + r;
                int row = r0 + rowl;
                float v = acc[i][j][r];
                if (row < N_NODES)
                    h1b[(size_t)row * HID + colc] = f2bf(v);
                atomicAdd(&part[rowl][hl][0], v * av);
                atomicAdd(&part[rowl][hl][1], v * dv);
            }
        }
    __syncthreads();
#pragma unroll
    for (int i = 0; i < 2; i++) {
        int idx = tid + i * 256;                // 0..511
        int rowl = idx >> 2, hl = idx & 3;
        int row = r0 + rowl;
        if (row < N_NODES) {
            int h = hb4 + hl;
            as1[(size_t)row * HEADS + h] = part[rowl][hl][0];
            ad1[(size_t)row * HEADS + h] = part[rowl][hl][1];
        }
    }
}

// ------- GEMM2 (MFMA, split-K x2 in-block, BK=64, fused combine + bf16 cast + alpha2 dots) -------
// 512 threads = 8 waves; waves 0-3: K[0,704), waves 4-7: K[704,1408). 32 rows x 128 cols.
__global__ __launch_bounds__(512) void k_gemm2(const unsigned short* __restrict__ A,
                                               const unsigned short* __restrict__ W2T,
                                               const float* __restrict__ a_src2,
                                               const float* __restrict__ a_dst2,
                                               unsigned short* __restrict__ h2q,
                                               float* __restrict__ as2,
                                               float* __restrict__ ad2) {
    __shared__ unsigned short As[2][32][72];
    __shared__ unsigned short Bs[2][128][72];
    __shared__ float Cs[32][132];
    int tid = threadIdx.x;
    int r0 = blockIdx.x * 32;                 // 625*32 = 20000 exact
    int khalf = tid >> 8;                     // 0 or 1
    int tl = tid & 255;
    int lane = tid & 63;
    int wl = (tid >> 6) & 3;
    int quad = lane >> 4, l15 = lane & 15;
    int nbase = wl * 32;
    int kbase = khalf * 704;
    floatx4 acc[2][2];
#pragma unroll
    for (int i = 0; i < 2; i++)
#pragma unroll
        for (int j = 0; j < 2; j++) acc[i][j] = (floatx4){0.f, 0.f, 0.f, 0.f};

    for (int it = 0; it < 11; it++) {
        int k0 = kbase + it * 64;
        __syncthreads();
        {
            int row = tl >> 3, kc = (tl & 7) * 8;    // 32 rows x 64 K
            *(bf16x8*)&As[khalf][row][kc] = *(const bf16x8*)(A + (size_t)(r0 + row) * KP2 + k0 + kc);
        }
#pragma unroll
        for (int i = 0; i < 4; i++) {
            int c = tl + i * 256;                    // 128 rows x 64 K
            int row = c >> 3, kc = (c & 7) * 8;
            *(bf16x8*)&Bs[khalf][row][kc] = *(const bf16x8*)(W2T + (size_t)row * KP2 + k0 + kc);
        }
        __syncthreads();
#pragma unroll
        for (int kk = 0; kk < 64; kk += 32) {
            bf16x8 a0 = *(const bf16x8*)&As[khalf][l15][kk + quad * 8];
            bf16x8 a1 = *(const bf16x8*)&As[khalf][16 + l15][kk + quad * 8];
            bf16x8 b0 = *(const bf16x8*)&Bs[khalf][nbase + l15][kk + quad * 8];
            bf16x8 b1 = *(const bf16x8*)&Bs[khalf][nbase + 16 + l15][kk + quad * 8];
            acc[0][0] = __builtin_amdgcn_mfma_f32_16x16x32_bf16(a0, b0, acc[0][0], 0, 0, 0);
            acc[1][0] = __builtin_amdgcn_mfma_f32_16x16x32_bf16(a1, b0, acc[1][0], 0, 0, 0);
            acc[0][1] = __builtin_amdgcn_mfma_f32_16x16x32_bf16(a0, b1, acc[0][1], 0, 0, 0);
            acc[1][1] = __builtin_amdgcn_mfma_f32_16x16x32_bf16(a1, b1, acc[1][1], 0, 0, 0);
        }
    }
    __syncthreads();
    if (khalf == 0) {
#pragma unroll
        for (int i = 0; i < 2; i++)
#pragma unroll
            for (int j = 0; j < 2; j++)
#pragma unroll
                for (int r = 0; r < 4; r++)
                    Cs[i * 16 + quad * 4 + r][nbase + j * 16 + l15] = acc[i][j][r];
    }
    __syncthreads();
    if (khalf == 1) {
#pragma unroll
        for (int i = 0; i < 2; i++)
#pragma unroll
            for (int j = 0; j < 2; j++)
#pragma unroll
                for (int r = 0; r < 4; r++)
                    Cs[i * 16 + quad * 4 + r][nbase + j * 16 + l15] += acc[i][j][r];
    }
    __syncthreads();
    {
        int row = tid >> 4;
        int c8 = (tid & 15) * 8;
        float v[8];
        ushort8 o;
        float ss = 0.f, sd = 0.f;
#pragma unroll
        for (int j = 0; j < 8; j++) {
            v[j] = Cs[row][c8 + j];
            o[j] = f2bf(v[j]);
            ss = fmaf(v[j], a_src2[c8 + j], ss);
            sd = fmaf(v[j], a_dst2[c8 + j], sd);
        }
        *(ushort8*)(h2q + (size_t)(r0 + row) * OUT_CH + c8) = o;
#pragma unroll
        for (int off = 8; off > 0; off >>= 1) {
            ss += __shfl_down(ss, off);
            sd += __shfl_down(sd, off);
        }
        if ((tid & 15) == 0) {
            as2[r0 + row] = ss;
            ad2[r0 + row] = sd;
        }
    }
}

// ---------------- CSR build ----------------
__global__ __launch_bounds__(1024) void k_scan(const int* __restrict__ cnt, int* __restrict__ rowp) {
    __shared__ int sh[1024];
    const int PER = 20;
    int t = threadIdx.x;
    int base = t * PER;
    int local[PER];
    int sum = 0;
    for (int i = 0; i < PER; i++) {
        int idx = base + i;
        int v = (idx < N_NODES) ? cnt[idx] : 0;
        local[i] = sum;
        sum += v;
    }
    sh[t] = sum;
    __syncthreads();
    for (int off = 1; off < 1024; off <<= 1) {
        int v = (t >= off) ? sh[t - off] : 0;
        __syncthreads();
        sh[t] += v;
        __syncthreads();
    }
    int offset = (t == 0) ? 0 : sh[t - 1];
    for (int i = 0; i < PER; i++) {
        int idx = base + i;
        if (idx < N_NODES) rowp[idx] = offset + local[i];
    }
    if (t == 1023) rowp[N_NODES] = sh[1023];
}

__global__ void k_fill(const int* __restrict__ ei, const int* __restrict__ rowp,
                       int* __restrict__ cursor, int* __restrict__ col) {
    int e = blockIdx.x * 256 + threadIdx.x;
    if (e >= ET) return;
    int s, d;
    if (e < E_EDGES) { s = ei[e]; d = ei[E_EDGES + e]; }
    else { s = e - E_EDGES; d = s; }
    int pos = rowp[d] + atomicAdd(&cursor[d], 1);
    col[pos] = s;
}

// ---------------- agg1: fused softmax + gather, post-normalization ----------------
__global__ __launch_bounds__(192) void k_agg1(const unsigned short* __restrict__ h1b,
                                              const float* __restrict__ as1,
                                              const float* __restrict__ ad1,
                                              const int* __restrict__ rowp,
                                              const int* __restrict__ col,
                                              const float* __restrict__ b1,
                                              unsigned short* __restrict__ out1b) {
    int n = blockIdx.x;
    int tid = threadIdx.x;
    int r0 = rowp[n], r1 = rowp[n + 1];
    const bool act = tid < 162;
    int c0 = tid * 8;
    int h0 = act ? c0 / 36 : 0;
    int h7 = act ? (c0 + 7) / 36 : 0;
    int split = (h0 + 1) * 36 - c0;       // elements j < split belong to head h0
    float sel[8];
#pragma unroll
    for (int j = 0; j < 8; j++) sel[j] = (j < split) ? 0.f : 1.f;
    float ad0 = 0.f, ad7 = 0.f;
    if (act) {
        ad0 = ad1[(size_t)n * HEADS + h0];
        ad7 = (h7 == h0) ? ad0 : ad1[(size_t)n * HEADS + h7];
    }
    float acc[8];
#pragma unroll
    for (int j = 0; j < 8; j++) acc[j] = 0.f;
    float sA = 0.f, sB = 0.f;

    if (act) {
        int e = r0;
        for (; e + 4 <= r1; e += 4) {
            int s0 = col[e], s1 = col[e + 1], s2 = col[e + 2], s3 = col[e + 3];
            float wA0 = __expf(lrelu(as1[(size_t)s0 * HEADS + h0] + ad0));
            float wB0 = __expf(lrelu(as1[(size_t)s0 * HEADS + h7] + ad7));
            float wA1 = __expf(lrelu(as1[(size_t)s1 * HEADS + h0] + ad0));
            float wB1 = __expf(lrelu(as1[(size_t)s1 * HEADS + h7] + ad7));
            float wA2 = __expf(lrelu(as1[(size_t)s2 * HEADS + h0] + ad0));
            float wB2 = __expf(lrelu(as1[(size_t)s2 * HEADS + h7] + ad7));
            float wA3 = __expf(lrelu(as1[(size_t)s3 * HEADS + h0] + ad0));
            float wB3 = __expf(lrelu(as1[(size_t)s3 * HEADS + h7] + ad7));
            ushort8 v0 = *(const ushort8*)(h1b + (size_t)s0 * HID + c0);
            ushort8 v1 = *(const ushort8*)(h1b + (size_t)s1 * HID + c0);
            ushort8 v2 = *(const ushort8*)(h1b + (size_t)s2 * HID + c0);
            ushort8 v3 = *(const ushort8*)(h1b + (size_t)s3 * HID + c0);
            sA += wA0 + wA1 + wA2 + wA3;
            sB += wB0 + wB1 + wB2 + wB3;
            float dw0 = wB0 - wA0, dw1 = wB1 - wA1, dw2 = wB2 - wA2, dw3 = wB3 - wA3;
#pragma unroll
            for (int j = 0; j < 8; j++) {
                acc[j] = fmaf(fmaf(sel[j], dw0, wA0), bf2f(v0[j]), acc[j]);
                acc[j] = fmaf(fmaf(sel[j], dw1, wA1), bf2f(v1[j]), acc[j]);
                acc[j] = fmaf(fmaf(sel[j], dw2, wA2), bf2f(v2[j]), acc[j]);
                acc[j] = fmaf(fmaf(sel[j], dw3, wA3), bf2f(v3[j]), acc[j]);
            }
        }
        for (; e < r1; e++) {
            int s = col[e];
            float wA = __expf(lrelu(as1[(size_t)s * HEADS + h0] + ad0));
            float wB = __expf(lrelu(as1[(size_t)s * HEADS + h7] + ad7));
            ushort8 vv = *(const ushort8*)(h1b + (size_t)s * HID + c0);
            sA += wA; sB += wB;
            float dw = wB - wA;
#pragma unroll
            for (int j = 0; j < 8; j++)
                acc[j] = fmaf(fmaf(sel[j], dw, wA), bf2f(vv[j]), acc[j]);
        }
    }
    if (tid < KP2 / 8) {                     // 176 slots incl. 14 zero-pad
        ushort8 o;
        if (act) {
            float invA = 1.f / (sA + 1e-16f);
            float invB = 1.f / (sB + 1e-16f);
            float dinv = invB - invA;
#pragma unroll
            for (int j = 0; j < 8; j++) {
                float vv = acc[j] * fmaf(sel[j], dinv, invA) + b1[c0 + j];
                o[j] = f2bf(fmaxf(vv, 0.f));
            }
        } else {
#pragma unroll
            for (int j = 0; j < 8; j++) o[j] = 0;
        }
        *(ushort8*)(out1b + (size_t)n * KP2 + c0) = o;
    }
}

// ------- agg2: wave-per-node, barrier-free (shfl staging) -------
__global__ __launch_bounds__(64) void k_agg2(const unsigned short* __restrict__ h2q,
                                             const float* __restrict__ as,
                                             const float* __restrict__ ad,
                                             const int* __restrict__ rowp,
                                             const int* __restrict__ col,
                                             const float* __restrict__ b2,
                                             float* __restrict__ out) {
    int n = blockIdx.x;
    int t = threadIdx.x;
    int r0 = rowp[n], r1 = rowp[n + 1];
    float adn = ad[n];
    float acc0 = 0.f, acc1 = 0.f;
    float sw = 0.f;
    for (int p0 = r0; p0 < r1; p0 += 64) {
        int ne = min(64, r1 - p0);
        int s_lane = 0;
        float w_lane = 0.f;
        if (t < ne) {
            s_lane = col[p0 + t];
            w_lane = __expf(lrelu(as[s_lane] + adn));
        }
        for (int e = 0; e < ne; e += 4) {
            int s0 = __shfl(s_lane, e + 0); float w0 = __shfl(w_lane, e + 0);
            int s1 = __shfl(s_lane, e + 1); float w1 = __shfl(w_lane, e + 1);
            int s2 = __shfl(s_lane, e + 2); float w2 = __shfl(w_lane, e + 2);
            int s3 = __shfl(s_lane, e + 3); float w3 = __shfl(w_lane, e + 3);
            uint u0 = *(const uint*)(h2q + (size_t)s0 * OUT_CH + t * 2);
            uint u1 = *(const uint*)(h2q + (size_t)s1 * OUT_CH + t * 2);
            uint u2 = *(const uint*)(h2q + (size_t)s2 * OUT_CH + t * 2);
            uint u3 = *(const uint*)(h2q + (size_t)s3 * OUT_CH + t * 2);
            sw += w0 + w1 + w2 + w3;
            acc0 += w0 * bf2f((unsigned short)(u0 & 0xFFFF)) + w1 * bf2f((unsigned short)(u1 & 0xFFFF))
                  + w2 * bf2f((unsigned short)(u2 & 0xFFFF)) + w3 * bf2f((unsigned short)(u3 & 0xFFFF));
            acc1 += w0 * bf2f((unsigned short)(u0 >> 16)) + w1 * bf2f((unsigned short)(u1 >> 16))
                  + w2 * bf2f((unsigned short)(u2 >> 16)) + w3 * bf2f((unsigned short)(u3 >> 16));
        }
    }
    float inv = 1.f / (sw + 1e-16f);
    float o0 = acc0 * inv + b2[t * 2];
    float o1 = acc1 * inv + b2[t * 2 + 1];
    out[(size_t)n * OUT_CH + t * 2]     = (o0 > 0.f) ? o0 : 0.f;
    out[(size_t)n * OUT_CH + t * 2 + 1] = (o1 > 0.f) ? o1 : 0.f;
}

extern "C" void kernel_launch(void* const* d_in, const int* in_sizes, int n_in,
                              void* d_out, int out_size, void* d_ws, size_t ws_size,
                              hipStream_t stream) {
    const float* x      = (const float*)d_in[0];
    const int*   ei     = (const int*)d_in[1];
    const float* W1     = (const float*)d_in[2];
    const float* a_src1 = (const float*)d_in[3];
    const float* a_dst1 = (const float*)d_in[4];
    const float* b1     = (const float*)d_in[5];
    const float* W2     = (const float*)d_in[6];
    const float* a_src2 = (const float*)d_in[7];
    const float* a_dst2 = (const float*)d_in[8];
    const float* b2     = (const float*)d_in[9];
    float* out = (float*)d_out;

    // ---- workspace layout (cnt+cursor are one contiguous memset region) ----
    unsigned short* h1b   = (unsigned short*)d_ws;                 // 25,920,000 ush
    unsigned short* out1b = h1b + (size_t)N_NODES * HID;           // 28,160,000 ush (N*KP2)
    unsigned short* xb    = out1b + (size_t)N_NODES * KP2;         // 2,560,000
    unsigned short* W1T   = xb + (size_t)N_NODES * IN_CH;          // 165,888
    unsigned short* W2T   = W1T + (size_t)HID * IN_CH;             // 180,224
    float* fbase = (float*)(W2T + NW2);
    float* as1  = fbase;                                           // 720,000
    float* ad1  = as1 + (size_t)N_NODES * HEADS;                   // 720,000
    unsigned short* h2q = (unsigned short*)(ad1 + (size_t)N_NODES * HEADS); // 2,560,000 ush
    float* as2  = (float*)(h2q + (size_t)N_NODES * OUT_CH);        // 20,000
    float* ad2  = as2 + N_NODES;                                   // 20,000
    int* cnt    = (int*)(ad2 + N_NODES);                           // 20,000 (memset start)
    int* cursor = cnt + N_NODES;                                   // 20,000 (memset)
    int* rowp   = cursor + N_NODES;                                // 20,001
    int* colx   = rowp + (N_NODES + 1);                            // 180,000

    hipMemsetAsync(cnt, 0, (size_t)(2 * N_NODES) * sizeof(int), stream);

    k_prepcnt<<<(NPREP + ET + 255) / 256, 256, 0, stream>>>(x, xb, W1, W1T, W2, W2T, ei, cnt);
    k_scan<<<1, 1024, 0, stream>>>(cnt, rowp);
    k_fill<<<(ET + 255) / 256, 256, 0, stream>>>(ei, rowp, cursor, colx);
    k_gemm1<<<dim3(157, 9), 256, 0, stream>>>(xb, W1T, a_src1, a_dst1, h1b, as1, ad1);
    k_agg1<<<N_NODES, 192, 0, stream>>>(h1b, as1, ad1, rowp, colx, b1, out1b);
    k_gemm2<<<625, 512, 0, stream>>>(out1b, W2T, a_src2, a_dst2, h2q, as2, ad2);
    k_agg2<<<N_NODES, 64, 0, stream>>>(h2q, as2, ad2, rowp, colx, b2, out);
}

// Round 15
// 268.696 us; speedup vs baseline: 2.2467x; 2.2467x over previous
//
#include <hip/hip_runtime.h>

#define N_NODES 20000
#define E_EDGES 160000
#define ET (E_EDGES + N_NODES)   // 180000 with self-loops
#define IN_CH 128
#define HID 1296
#define HEADS 36
#define CPH 36
#define OUT_CH 128
#define KP2 1408                 // HID padded to 2*704 (704=11*64) for gemm2 BK=64 split-K
#define NEG_SLOPE 0.2f

typedef __attribute__((ext_vector_type(8))) short bf16x8;
typedef __attribute__((ext_vector_type(8))) unsigned short ushort8;
typedef __attribute__((ext_vector_type(4))) float floatx4;

__device__ __forceinline__ float bf2f(unsigned short u) {
    union { unsigned int i; float f; } c; c.i = ((unsigned int)u) << 16; return c.f;
}
__device__ __forceinline__ unsigned short f2bf(float f) {
    union { float f; unsigned int i; } c; c.f = f;
    unsigned int r = c.i + 0x7FFF + ((c.i >> 16) & 1);   // round-to-nearest-even
    return (unsigned short)(r >> 16);
}
__device__ __forceinline__ float lrelu(float v) {
    return (v > 0.f) ? v : NEG_SLOPE * v;
}

// ------- prep+count (fused, range-partitioned): casts + degree count -------
#define NX (N_NODES * IN_CH / 4)      // 640000 float4 units
#define NW1 (HID * IN_CH)             // 165888
#define NW2 (OUT_CH * KP2)            // 180224
#define NPREP (NX + NW1 + NW2)
__global__ __launch_bounds__(256) void k_prepcnt(const float* __restrict__ x,
                                                 unsigned short* __restrict__ xb,
                                                 const float* __restrict__ W1,
                                                 unsigned short* __restrict__ W1T,
                                                 const float* __restrict__ W2,
                                                 unsigned short* __restrict__ W2T,
                                                 const int* __restrict__ ei,
                                                 int* __restrict__ cnt) {
    int gid = blockIdx.x * 256 + threadIdx.x;
    if (gid < NX) {
        float4 v = ((const float4*)x)[gid];
        ushort4 o; o.x = f2bf(v.x); o.y = f2bf(v.y); o.z = f2bf(v.z); o.w = f2bf(v.w);
        ((ushort4*)xb)[gid] = o;
    } else if (gid < NX + NW1) {
        int g = gid - NX;
        int n = g >> 7, k = g & 127;
        W1T[g] = f2bf(W1[(size_t)k * HID + n]);
    } else if (gid < NPREP) {
        int g = gid - NX - NW1;
        int n = g / KP2, k = g - n * KP2;
        W2T[g] = (k < HID) ? f2bf(W2[(size_t)k * OUT_CH + n]) : 0;
    } else if (gid < NPREP + ET) {
        int e = gid - NPREP;
        int d = (e < E_EDGES) ? ei[E_EDGES + e] : (e - E_EDGES);
        atomicAdd(&cnt[d], 1);
    }
}

// ---------------- GEMM1 (MFMA): h1b[N,1296] = xb[N,128] @ W1T^T ----------------
__global__ __launch_bounds__(256) void k_gemm1(const unsigned short* __restrict__ xb,
                                               const unsigned short* __restrict__ W1T,
                                               unsigned short* __restrict__ h1b) {
    __shared__ unsigned short As[128][136];
    __shared__ unsigned short Bs[64][136];
    int tid = threadIdx.x;
    int r0 = blockIdx.x * 128;
    int n0 = blockIdx.y * 64;
#pragma unroll
    for (int i = 0; i < 8; i++) {
        int c = tid + i * 256;
        int row = c >> 4, kc = (c & 15) * 8;
        int gr = min(r0 + row, N_NODES - 1);
        *(bf16x8*)&As[row][kc] = *(const bf16x8*)(xb + (size_t)gr * IN_CH + kc);
    }
#pragma unroll
    for (int i = 0; i < 4; i++) {
        int c = tid + i * 256;
        int row = c >> 4, kc = (c & 15) * 8;
        int gn = min(n0 + row, HID - 1);
        *(bf16x8*)&Bs[row][kc] = *(const bf16x8*)(W1T + (size_t)gn * IN_CH + kc);
    }
    __syncthreads();
    int lane = tid & 63, w = tid >> 6;
    int quad = lane >> 4, l15 = lane & 15;
    int mbase = w * 32;
    floatx4 acc[2][4];
#pragma unroll
    for (int i = 0; i < 2; i++)
#pragma unroll
        for (int j = 0; j < 4; j++) acc[i][j] = (floatx4){0.f, 0.f, 0.f, 0.f};
#pragma unroll
    for (int kc = 0; kc < 128; kc += 32) {
        bf16x8 a0 = *(const bf16x8*)&As[mbase + l15][kc + quad * 8];
        bf16x8 a1 = *(const bf16x8*)&As[mbase + 16 + l15][kc + quad * 8];
#pragma unroll
        for (int j = 0; j < 4; j++) {
            bf16x8 b = *(const bf16x8*)&Bs[j * 16 + l15][kc + quad * 8];
            acc[0][j] = __builtin_amdgcn_mfma_f32_16x16x32_bf16(a0, b, acc[0][j], 0, 0, 0);
            acc[1][j] = __builtin_amdgcn_mfma_f32_16x16x32_bf16(a1, b, acc[1][j], 0, 0, 0);
        }
    }
#pragma unroll
    for (int i = 0; i < 2; i++)
#pragma unroll
        for (int j = 0; j < 4; j++) {
            int colc = n0 + j * 16 + l15;
            if (colc >= HID) continue;
#pragma unroll
            for (int r = 0; r < 4; r++) {
                int row = r0 + mbase + i * 16 + quad * 4 + r;
                if (row < N_NODES)
                    h1b[(size_t)row * HID + colc] = f2bf(acc[i][j][r]);
            }
        }
}

// ------- GEMM2 (MFMA, split-K x2 in-block, BK=64, fused combine + bf16 cast + alpha2 dots) -------
__global__ __launch_bounds__(512) void k_gemm2(const unsigned short* __restrict__ A,
                                               const unsigned short* __restrict__ W2T,
                                               const float* __restrict__ a_src2,
                                               const float* __restrict__ a_dst2,
                                               unsigned short* __restrict__ h2q,
                                               float* __restrict__ as2,
                                               float* __restrict__ ad2) {
    __shared__ unsigned short As[2][32][72];
    __shared__ unsigned short Bs[2][128][72];
    __shared__ float Cs[32][132];
    int tid = threadIdx.x;
    int r0 = blockIdx.x * 32;                 // 625*32 = 20000 exact
    int khalf = tid >> 8;                     // 0 or 1
    int tl = tid & 255;
    int lane = tid & 63;
    int wl = (tid >> 6) & 3;
    int quad = lane >> 4, l15 = lane & 15;
    int nbase = wl * 32;
    int kbase = khalf * 704;
    floatx4 acc[2][2];
#pragma unroll
    for (int i = 0; i < 2; i++)
#pragma unroll
        for (int j = 0; j < 2; j++) acc[i][j] = (floatx4){0.f, 0.f, 0.f, 0.f};

    for (int it = 0; it < 11; it++) {
        int k0 = kbase + it * 64;
        __syncthreads();
        {
            int row = tl >> 3, kc = (tl & 7) * 8;    // 32 rows x 64 K
            *(bf16x8*)&As[khalf][row][kc] = *(const bf16x8*)(A + (size_t)(r0 + row) * KP2 + k0 + kc);
        }
#pragma unroll
        for (int i = 0; i < 4; i++) {
            int c = tl + i * 256;                    // 128 rows x 64 K
            int row = c >> 3, kc = (c & 7) * 8;
            *(bf16x8*)&Bs[khalf][row][kc] = *(const bf16x8*)(W2T + (size_t)row * KP2 + k0 + kc);
        }
        __syncthreads();
#pragma unroll
        for (int kk = 0; kk < 64; kk += 32) {
            bf16x8 a0 = *(const bf16x8*)&As[khalf][l15][kk + quad * 8];
            bf16x8 a1 = *(const bf16x8*)&As[khalf][16 + l15][kk + quad * 8];
            bf16x8 b0 = *(const bf16x8*)&Bs[khalf][nbase + l15][kk + quad * 8];
            bf16x8 b1 = *(const bf16x8*)&Bs[khalf][nbase + 16 + l15][kk + quad * 8];
            acc[0][0] = __builtin_amdgcn_mfma_f32_16x16x32_bf16(a0, b0, acc[0][0], 0, 0, 0);
            acc[1][0] = __builtin_amdgcn_mfma_f32_16x16x32_bf16(a1, b0, acc[1][0], 0, 0, 0);
            acc[0][1] = __builtin_amdgcn_mfma_f32_16x16x32_bf16(a0, b1, acc[0][1], 0, 0, 0);
            acc[1][1] = __builtin_amdgcn_mfma_f32_16x16x32_bf16(a1, b1, acc[1][1], 0, 0, 0);
        }
    }
    __syncthreads();
    if (khalf == 0) {
#pragma unroll
        for (int i = 0; i < 2; i++)
#pragma unroll
            for (int j = 0; j < 2; j++)
#pragma unroll
                for (int r = 0; r < 4; r++)
                    Cs[i * 16 + quad * 4 + r][nbase + j * 16 + l15] = acc[i][j][r];
    }
    __syncthreads();
    if (khalf == 1) {
#pragma unroll
        for (int i = 0; i < 2; i++)
#pragma unroll
            for (int j = 0; j < 2; j++)
#pragma unroll
                for (int r = 0; r < 4; r++)
                    Cs[i * 16 + quad * 4 + r][nbase + j * 16 + l15] += acc[i][j][r];
    }
    __syncthreads();
    {
        int row = tid >> 4;
        int c8 = (tid & 15) * 8;
        float v[8];
        ushort8 o;
        float ss = 0.f, sd = 0.f;
#pragma unroll
        for (int j = 0; j < 8; j++) {
            v[j] = Cs[row][c8 + j];
            o[j] = f2bf(v[j]);
            ss = fmaf(v[j], a_src2[c8 + j], ss);
            sd = fmaf(v[j], a_dst2[c8 + j], sd);
        }
        *(ushort8*)(h2q + (size_t)(r0 + row) * OUT_CH + c8) = o;
#pragma unroll
        for (int off = 8; off > 0; off >>= 1) {
            ss += __shfl_down(ss, off);
            sd += __shfl_down(sd, off);
        }
        if ((tid & 15) == 0) {
            as2[r0 + row] = ss;
            ad2[r0 + row] = sd;
        }
    }
}

// ---------------- alpha1: per (node,head) dot over 36 channels (bf16 input) ----------------
__global__ __launch_bounds__(256) void k_alpha1(const unsigned short* __restrict__ h1b,
                                                const float* __restrict__ a_src,
                                                const float* __restrict__ a_dst,
                                                float* __restrict__ as,
                                                float* __restrict__ ad) {
    __shared__ float s_a[HEADS * CPH], s_b[HEADS * CPH];
    int tid = threadIdx.x;
    for (int i = tid; i < HEADS * CPH; i += 256) { s_a[i] = a_src[i]; s_b[i] = a_dst[i]; }
    __syncthreads();
    int gid = blockIdx.x * 256 + tid;
    if (gid >= N_NODES * HEADS) return;
    int n = gid / HEADS, h = gid - n * HEADS;
    const unsigned short* row = h1b + (size_t)n * HID + h * CPH;
    float ss = 0.f, sd = 0.f;
#pragma unroll
    for (int c = 0; c < CPH; c += 2) {
        uint u = *(const uint*)(row + c);
        float v0 = bf2f((unsigned short)(u & 0xFFFF));
        float v1 = bf2f((unsigned short)(u >> 16));
        ss += v0 * s_a[h * CPH + c] + v1 * s_a[h * CPH + c + 1];
        sd += v0 * s_b[h * CPH + c] + v1 * s_b[h * CPH + c + 1];
    }
    as[gid] = ss;
    ad[gid] = sd;
}

// ---------------- CSR build ----------------
__global__ __launch_bounds__(1024) void k_scan(const int* __restrict__ cnt, int* __restrict__ rowp) {
    __shared__ int sh[1024];
    const int PER = 20;
    int t = threadIdx.x;
    int base = t * PER;
    int local[PER];
    int sum = 0;
    for (int i = 0; i < PER; i++) {
        int idx = base + i;
        int v = (idx < N_NODES) ? cnt[idx] : 0;
        local[i] = sum;
        sum += v;
    }
    sh[t] = sum;
    __syncthreads();
    for (int off = 1; off < 1024; off <<= 1) {
        int v = (t >= off) ? sh[t - off] : 0;
        __syncthreads();
        sh[t] += v;
        __syncthreads();
    }
    int offset = (t == 0) ? 0 : sh[t - 1];
    for (int i = 0; i < PER; i++) {
        int idx = base + i;
        if (idx < N_NODES) rowp[idx] = offset + local[i];
    }
    if (t == 1023) rowp[N_NODES] = sh[1023];
}

__global__ void k_fill(const int* __restrict__ ei, const int* __restrict__ rowp,
                       int* __restrict__ cursor, int* __restrict__ col) {
    int e = blockIdx.x * 256 + threadIdx.x;
    if (e >= ET) return;
    int s, d;
    if (e < E_EDGES) { s = ei[e]; d = ei[E_EDGES + e]; }
    else { s = e - E_EDGES; d = s; }
    int pos = rowp[d] + atomicAdd(&cursor[d], 1);
    col[pos] = s;
}

// ---------------- agg1: fused softmax + gather, post-normalization ----------------
__global__ __launch_bounds__(192) void k_agg1(const unsigned short* __restrict__ h1b,
                                              const float* __restrict__ as1,
                                              const float* __restrict__ ad1,
                                              const int* __restrict__ rowp,
                                              const int* __restrict__ col,
                                              const float* __restrict__ b1,
                                              unsigned short* __restrict__ out1b) {
    int n = blockIdx.x;
    int tid = threadIdx.x;
    int r0 = rowp[n], r1 = rowp[n + 1];
    const bool act = tid < 162;
    int c0 = tid * 8;
    int h0 = act ? c0 / 36 : 0;
    int h7 = act ? (c0 + 7) / 36 : 0;
    int split = (h0 + 1) * 36 - c0;       // elements j < split belong to head h0
    float sel[8];
#pragma unroll
    for (int j = 0; j < 8; j++) sel[j] = (j < split) ? 0.f : 1.f;
    float ad0 = 0.f, ad7 = 0.f;
    if (act) {
        ad0 = ad1[(size_t)n * HEADS + h0];
        ad7 = (h7 == h0) ? ad0 : ad1[(size_t)n * HEADS + h7];
    }
    float acc[8];
#pragma unroll
    for (int j = 0; j < 8; j++) acc[j] = 0.f;
    float sA = 0.f, sB = 0.f;

    if (act) {
        int e = r0;
        for (; e + 4 <= r1; e += 4) {
            int s0 = col[e], s1 = col[e + 1], s2 = col[e + 2], s3 = col[e + 3];
            float wA0 = __expf(lrelu(as1[(size_t)s0 * HEADS + h0] + ad0));
            float wB0 = __expf(lrelu(as1[(size_t)s0 * HEADS + h7] + ad7));
            float wA1 = __expf(lrelu(as1[(size_t)s1 * HEADS + h0] + ad0));
            float wB1 = __expf(lrelu(as1[(size_t)s1 * HEADS + h7] + ad7));
            float wA2 = __expf(lrelu(as1[(size_t)s2 * HEADS + h0] + ad0));
            float wB2 = __expf(lrelu(as1[(size_t)s2 * HEADS + h7] + ad7));
            float wA3 = __expf(lrelu(as1[(size_t)s3 * HEADS + h0] + ad0));
            float wB3 = __expf(lrelu(as1[(size_t)s3 * HEADS + h7] + ad7));
            ushort8 v0 = *(const ushort8*)(h1b + (size_t)s0 * HID + c0);
            ushort8 v1 = *(const ushort8*)(h1b + (size_t)s1 * HID + c0);
            ushort8 v2 = *(const ushort8*)(h1b + (size_t)s2 * HID + c0);
            ushort8 v3 = *(const ushort8*)(h1b + (size_t)s3 * HID + c0);
            sA += wA0 + wA1 + wA2 + wA3;
            sB += wB0 + wB1 + wB2 + wB3;
            float dw0 = wB0 - wA0, dw1 = wB1 - wA1, dw2 = wB2 - wA2, dw3 = wB3 - wA3;
#pragma unroll
            for (int j = 0; j < 8; j++) {
                acc[j] = fmaf(fmaf(sel[j], dw0, wA0), bf2f(v0[j]), acc[j]);
                acc[j] = fmaf(fmaf(sel[j], dw1, wA1), bf2f(v1[j]), acc[j]);
                acc[j] = fmaf(fmaf(sel[j], dw2, wA2), bf2f(v2[j]), acc[j]);
                acc[j] = fmaf(fmaf(sel[j], dw3, wA3), bf2f(v3[j]), acc[j]);
            }
        }
        for (; e < r1; e++) {
            int s = col[e];
            float wA = __expf(lrelu(as1[(size_t)s * HEADS + h0] + ad0));
            float wB = __expf(lrelu(as1[(size_t)s * HEADS + h7] + ad7));
            ushort8 vv = *(const ushort8*)(h1b + (size_t)s * HID + c0);
            sA += wA; sB += wB;
            float dw = wB - wA;
#pragma unroll
            for (int j = 0; j < 8; j++)
                acc[j] = fmaf(fmaf(sel[j], dw, wA), bf2f(vv[j]), acc[j]);
        }
    }
    if (tid < KP2 / 8) {                     // 176 slots incl. 14 zero-pad
        ushort8 o;
        if (act) {
            float invA = 1.f / (sA + 1e-16f);
            float invB = 1.f / (sB + 1e-16f);
            float dinv = invB - invA;
#pragma unroll
            for (int j = 0; j < 8; j++) {
                float vv = acc[j] * fmaf(sel[j], dinv, invA) + b1[c0 + j];
                o[j] = f2bf(fmaxf(vv, 0.f));
            }
        } else {
#pragma unroll
            for (int j = 0; j < 8; j++) o[j] = 0;
        }
        *(ushort8*)(out1b + (size_t)n * KP2 + c0) = o;
    }
}

// ------- agg2: wave-per-node, barrier-free (shfl staging) -------
__global__ __launch_bounds__(64) void k_agg2(const unsigned short* __restrict__ h2q,
                                             const float* __restrict__ as,
                                             const float* __restrict__ ad,
                                             const int* __restrict__ rowp,
                                             const int* __restrict__ col,
                                             const float* __restrict__ b2,
                                             float* __restrict__ out) {
    int n = blockIdx.x;
    int t = threadIdx.x;
    int r0 = rowp[n], r1 = rowp[n + 1];
    float adn = ad[n];
    float acc0 = 0.f, acc1 = 0.f;
    float sw = 0.f;
    for (int p0 = r0; p0 < r1; p0 += 64) {
        int ne = min(64, r1 - p0);
        int s_lane = 0;
        float w_lane = 0.f;
        if (t < ne) {
            s_lane = col[p0 + t];
            w_lane = __expf(lrelu(as[s_lane] + adn));
        }
        for (int e = 0; e < ne; e += 4) {
            int s0 = __shfl(s_lane, e + 0); float w0 = __shfl(w_lane, e + 0);
            int s1 = __shfl(s_lane, e + 1); float w1 = __shfl(w_lane, e + 1);
            int s2 = __shfl(s_lane, e + 2); float w2 = __shfl(w_lane, e + 2);
            int s3 = __shfl(s_lane, e + 3); float w3 = __shfl(w_lane, e + 3);
            uint u0 = *(const uint*)(h2q + (size_t)s0 * OUT_CH + t * 2);
            uint u1 = *(const uint*)(h2q + (size_t)s1 * OUT_CH + t * 2);
            uint u2 = *(const uint*)(h2q + (size_t)s2 * OUT_CH + t * 2);
            uint u3 = *(const uint*)(h2q + (size_t)s3 * OUT_CH + t * 2);
            sw += w0 + w1 + w2 + w3;
            acc0 += w0 * bf2f((unsigned short)(u0 & 0xFFFF)) + w1 * bf2f((unsigned short)(u1 & 0xFFFF))
                  + w2 * bf2f((unsigned short)(u2 & 0xFFFF)) + w3 * bf2f((unsigned short)(u3 & 0xFFFF));
            acc1 += w0 * bf2f((unsigned short)(u0 >> 16)) + w1 * bf2f((unsigned short)(u1 >> 16))
                  + w2 * bf2f((unsigned short)(u2 >> 16)) + w3 * bf2f((unsigned short)(u3 >> 16));
        }
    }
    float inv = 1.f / (sw + 1e-16f);
    float o0 = acc0 * inv + b2[t * 2];
    float o1 = acc1 * inv + b2[t * 2 + 1];
    out[(size_t)n * OUT_CH + t * 2]     = (o0 > 0.f) ? o0 : 0.f;
    out[(size_t)n * OUT_CH + t * 2 + 1] = (o1 > 0.f) ? o1 : 0.f;
}

extern "C" void kernel_launch(void* const* d_in, const int* in_sizes, int n_in,
                              void* d_out, int out_size, void* d_ws, size_t ws_size,
                              hipStream_t stream) {
    const float* x      = (const float*)d_in[0];
    const int*   ei     = (const int*)d_in[1];
    const float* W1     = (const float*)d_in[2];
    const float* a_src1 = (const float*)d_in[3];
    const float* a_dst1 = (const float*)d_in[4];
    const float* b1     = (const float*)d_in[5];
    const float* W2     = (const float*)d_in[6];
    const float* a_src2 = (const float*)d_in[7];
    const float* a_dst2 = (const float*)d_in[8];
    const float* b2     = (const float*)d_in[9];
    float* out = (float*)d_out;

    // ---- workspace layout (cnt+cursor are one contiguous memset region) ----
    unsigned short* h1b   = (unsigned short*)d_ws;                 // 25,920,000 ush
    unsigned short* out1b = h1b + (size_t)N_NODES * HID;           // 28,160,000 ush (N*KP2)
    unsigned short* xb    = out1b + (size_t)N_NODES * KP2;         // 2,560,000
    unsigned short* W1T   = xb + (size_t)N_NODES * IN_CH;          // 165,888
    unsigned short* W2T   = W1T + (size_t)HID * IN_CH;             // 180,224
    float* fbase = (float*)(W2T + NW2);
    float* as1  = fbase;                                           // 720,000
    float* ad1  = as1 + (size_t)N_NODES * HEADS;                   // 720,000
    unsigned short* h2q = (unsigned short*)(ad1 + (size_t)N_NODES * HEADS); // 2,560,000 ush
    float* as2  = (float*)(h2q + (size_t)N_NODES * OUT_CH);        // 20,000
    float* ad2  = as2 + N_NODES;                                   // 20,000
    int* cnt    = (int*)(ad2 + N_NODES);                           // 20,000 (memset start)
    int* cursor = cnt + N_NODES;                                   // 20,000 (memset)
    int* rowp   = cursor + N_NODES;                                // 20,001
    int* colx   = rowp + (N_NODES + 1);                            // 180,000

    hipMemsetAsync(cnt, 0, (size_t)(2 * N_NODES) * sizeof(int), stream);

    k_prepcnt<<<(NPREP + ET + 255) / 256, 256, 0, stream>>>(x, xb, W1, W1T, W2, W2T, ei, cnt);
    k_scan<<<1, 1024, 0, stream>>>(cnt, rowp);
    k_fill<<<(ET + 255) / 256, 256, 0, stream>>>(ei, rowp, cursor, colx);
    k_gemm1<<<dim3(157, 21), 256, 0, stream>>>(xb, W1T, h1b);
    k_alpha1<<<(N_NODES * HEADS + 255) / 256, 256, 0, stream>>>(h1b, a_src1, a_dst1, as1, ad1);
    k_agg1<<<N_NODES, 192, 0, stream>>>(h1b, as1, ad1, rowp, colx, b1, out1b);
    k_gemm2<<<625, 512, 0, stream>>>(out1b, W2T, a_src2, a_dst2, h2q, as2, ad2);
    k_agg2<<<N_NODES, 64, 0, stream>>>(h2q, as2, ad2, rowp, colx, b2, out);
}